// Round 10
// baseline (241.033 us; speedup 1.0000x reference)
//
#include <hip/hip_runtime.h>
#include <hip/hip_bf16.h>

// Geometry fixed by reference: B=16, Lq=Lk=2048, D=Dv=64, fp32.
// d_out = out [16,2048,64] ++ w [16,2048,2048].
// DIAGNOSTIC ROUND: sdpa_all body repeated 3x (idempotent) so its rocprof
// counters rise above the harness's ~160us ws-poison fills in the top-5.
#define B_ 16
#define L_ 2048
#define D_ 64
#define NROWS (B_ * L_)

typedef _Float16 half8 __attribute__((ext_vector_type(8)));
typedef float    f32x4 __attribute__((ext_vector_type(4)));

__device__ __forceinline__ float fexp2(float x) {
    float r; asm("v_exp_f32 %0, %1" : "=v"(r) : "v"(x)); return r;
}
__device__ __forceinline__ unsigned umed3(unsigned a, unsigned b, unsigned c) {
    unsigned d; asm("v_med3_u32 %0, %1, %2, %3" : "=v"(d) : "v"(a), "v"(b), "v"(c));
    return d;
}
// monotone float -> uint order-preserving transform
__device__ __forceinline__ unsigned fkey(float x) {
    unsigned b = __float_as_uint(x);
    return b ^ ((unsigned)(((int)b) >> 31) | 0x80000000u);
}

// ---------------------------------------------------------------------------
// Kernel P: K fp32 -> fp16, row-major (row = 64 halves = 128 B).
// ---------------------------------------------------------------------------
__global__ __launch_bounds__(256)
void cvt_k(const float* __restrict__ k, _Float16* __restrict__ kext)
{
    size_t i = (size_t)blockIdx.x * 256 + threadIdx.x;   // 8 floats each
    const float4* src = reinterpret_cast<const float4*>(k) + i * 2;
    float4 a = src[0], b = src[1];
    half8 h = { (_Float16)a.x, (_Float16)a.y, (_Float16)a.z, (_Float16)a.w,
                (_Float16)b.x, (_Float16)b.y, (_Float16)b.z, (_Float16)b.w };
    *reinterpret_cast<half8*>(kext + i * 8) = h;
}

// ---------------------------------------------------------------------------
// Kernel A (R9 structure, body looped 3x for profiling visibility).
// ---------------------------------------------------------------------------
__global__ __launch_bounds__(256)
void sdpa_all(const float* __restrict__ q,
              const float* __restrict__ k,
              const float* __restrict__ v,
              const _Float16* __restrict__ kext,
              float* __restrict__ out,
              float* __restrict__ wout)
{
    __shared__ float Ms[2][64][21];   // wk-merge scratch (pad 21: bank-spread)
    __shared__ int4  Ri[32];          // per-row top-4 indices
    __shared__ float Rz[32];          // per-row Z (sum exp2)

    const int bid  = blockIdx.x;
    const int lbid = ((bid & 7) << 7) | (bid >> 3);   // XCD-contiguity swizzle
    const int tid  = threadIdx.x;
    const int b    = lbid >> 6;          // batch
    const int row0 = (lbid & 63) * 32;   // 32 rows per block
    const int w    = tid >> 6;
    const int lane = tid & 63;
    const int wr   = w & 1;              // row half (16 rows)
    const int wk   = w >> 1;             // key half (1024 keys)
    const int c    = lane & 15;
    const int g    = lane >> 4;

    const float CQ = 0.18033688011112042f;   // log2(e)/8
    float* wb = wout + ((size_t)b * L_ + row0) * L_;    // block's 256 KB slab

    // ---- Q fragment (A operand), loop-invariant ----
    half8 qf0, qf1;
    {
        const float* qr = q + ((size_t)(b * L_ + row0 + 16 * wr + c)) * D_ + 8 * g;
        float4 f0 = *reinterpret_cast<const float4*>(qr);
        float4 f1 = *reinterpret_cast<const float4*>(qr + 4);
        float4 f2 = *reinterpret_cast<const float4*>(qr + 32);
        float4 f3 = *reinterpret_cast<const float4*>(qr + 36);
        qf0 = half8{ (_Float16)(f0.x*CQ), (_Float16)(f0.y*CQ), (_Float16)(f0.z*CQ),
                     (_Float16)(f0.w*CQ), (_Float16)(f1.x*CQ), (_Float16)(f1.y*CQ),
                     (_Float16)(f1.z*CQ), (_Float16)(f1.w*CQ) };
        qf1 = half8{ (_Float16)(f2.x*CQ), (_Float16)(f2.y*CQ), (_Float16)(f2.z*CQ),
                     (_Float16)(f2.w*CQ), (_Float16)(f3.x*CQ), (_Float16)(f3.y*CQ),
                     (_Float16)(f3.z*CQ), (_Float16)(f3.w*CQ) };
    }

    const char* ke = (const char*)(kext + (size_t)b * L_ * D_);
    const f32x4 zz = {0.f, 0.f, 0.f, 0.f};
    f32x4* wb4 = reinterpret_cast<f32x4*>(wb);

    #pragma unroll 1
    for (int rep = 0; rep < 3; ++rep) {
        float    Z[4]  = {0.f, 0.f, 0.f, 0.f};
        unsigned tl[4][4];
        #pragma unroll
        for (int r = 0; r < 4; ++r)
            #pragma unroll
            for (int s = 0; s < 4; ++s) tl[r][s] = 0u;

        // sweep 1024 keys (this wave's half), 16 keys per step
        #pragma unroll 4
        for (int t = 0; t < 64; ++t) {
            const int kl = wk * 1024 + t * 16 + c;            // key id in batch
            const char* kp = ke + (size_t)kl * 128 + g * 16;
            half8 b0 = *reinterpret_cast<const half8*>(kp);        // d [8g,8g+8)
            half8 b1 = *reinterpret_cast<const half8*>(kp + 64);   // d [32+8g,..)

            // interleaved slab zero-fill: 4 KB per block per step
            __builtin_nontemporal_store(zz, wb4 + t * 256 + tid);

            f32x4 a = {0.f, 0.f, 0.f, 0.f};
            a = __builtin_amdgcn_mfma_f32_16x16x32_f16(qf0, b0, a, 0, 0, 0);
            a = __builtin_amdgcn_mfma_f32_16x16x32_f16(qf1, b1, a, 0, 0, 0);

            #pragma unroll
            for (int r = 0; r < 4; ++r) {
                float sp = a[r];                  // log2-domain score
                Z[r] += fexp2(sp);
                unsigned pk = (fkey(sp) & 0xFFFFF800u) | (unsigned)kl;
                unsigned n1 = umed3(pk, tl[r][0], tl[r][1]);
                unsigned n2 = umed3(pk, tl[r][1], tl[r][2]);
                unsigned n3 = umed3(pk, tl[r][2], tl[r][3]);
                tl[r][0] = max(tl[r][0], pk);
                tl[r][1] = n1; tl[r][2] = n2; tl[r][3] = n3;
            }
        }

        // ---- wk-pair merge through LDS ----
        if (wk == 1) {
            #pragma unroll
            for (int r = 0; r < 4; ++r) {
                Ms[wr][lane][r] = Z[r];
                #pragma unroll
                for (int s = 0; s < 4; ++s)
                    Ms[wr][lane][4 + r * 4 + s] = __uint_as_float(tl[r][s]);
            }
        }
        __syncthreads();   // Ms published; fill stores drained

        if (wk == 0) {
            #pragma unroll
            for (int r = 0; r < 4; ++r) {
                float Zr = Z[r] + Ms[wr][lane][r];
                #pragma unroll
                for (int s = 0; s < 4; ++s) {
                    unsigned pk = __float_as_uint(Ms[wr][lane][4 + r * 4 + s]);
                    unsigned n1 = umed3(pk, tl[r][0], tl[r][1]);
                    unsigned n2 = umed3(pk, tl[r][1], tl[r][2]);
                    unsigned n3 = umed3(pk, tl[r][2], tl[r][3]);
                    tl[r][0] = max(tl[r][0], pk);
                    tl[r][1] = n1; tl[r][2] = n2; tl[r][3] = n3;
                }
                #pragma unroll
                for (int m = 8; m; m >>= 1) Zr += __shfl_xor(Zr, m, 16);

                // 16-lane tournament: global top-4 (packed keys unique)
                int p = 0;
                unsigned win[4];
                #pragma unroll
                for (int t4 = 0; t4 < 4; ++t4) {
                    unsigned cand = (p == 0) ? tl[r][0] : (p == 1) ? tl[r][1]
                                  : (p == 2) ? tl[r][2] : (p == 3) ? tl[r][3] : 0u;
                    unsigned mv = cand;
                    #pragma unroll
                    for (int m = 8; m; m >>= 1) {
                        unsigned ov = __shfl_xor(mv, m, 16);
                        mv = mv > ov ? mv : ov;
                    }
                    win[t4] = mv;
                    if (cand == mv) ++p;
                }

                if (c == 0) {
                    int rr = 16 * wr + 4 * g + r;
                    Ri[rr] = make_int4((int)(win[0] & 2047u), (int)(win[1] & 2047u),
                                       (int)(win[2] & 2047u), (int)(win[3] & 2047u));
                    Rz[rr] = Zr;
                }
            }
        }
        __syncthreads();

        // ---- phase 3: exact fp32 rescore + weights + out + scatter ----
        const float* kb = k + (size_t)b * L_ * D_;
        const float* vb = v + (size_t)b * L_ * D_;
        #pragma unroll 2
        for (int rloc = 0; rloc < 8; ++rloc) {
            const int rr = w * 8 + rloc;
            const int gr = b * L_ + row0 + rr;
            int4  iv = Ri[rr];
            float Zr = Rz[rr];
            int myi = (g == 0) ? iv.x : (g == 1) ? iv.y : (g == 2) ? iv.z : iv.w;

            float4 qv = *reinterpret_cast<const float4*>(q + (size_t)gr * D_ + 4 * c);
            float4 kv = *reinterpret_cast<const float4*>(kb + (size_t)myi * D_ + 4 * c);
            float tp = qv.x * kv.x + qv.y * kv.y + qv.z * kv.z + qv.w * kv.w;
            #pragma unroll
            for (int m = 8; m; m >>= 1) tp += __shfl_xor(tp, m, 16);
            tp *= CQ;   // log2-domain exact score

            float t0 = __shfl(tp, 0), t1 = __shfl(tp, 16),
                  t2 = __shfl(tp, 32), t3 = __shfl(tp, 48);

            // P_j = Z * p_j ; all w math scaled by Z (exactly equivalent)
            float P0 = fexp2(t0), P1 = fexp2(t1), P2 = fexp2(t2), P3 = fexp2(t3);
            float Pmin = fminf(fminf(P0, P1), fminf(P2, P3));
            float eZ = 1e-7f * Zr;
            float n0 = fmaxf(P0 - Pmin - eZ, 0.f);
            float n1 = fmaxf(P1 - Pmin - eZ, 0.f);
            float n2 = fmaxf(P2 - Pmin - eZ, 0.f);
            float n3 = fmaxf(P3 - Pmin - eZ, 0.f);
            float wi = 1.0f / (n0 + n1 + n2 + n3 + eZ);
            float w0 = n0 * wi, w1 = n1 * wi, w2 = n2 * wi, w3 = n3 * wi;

            float o = w0 * vb[(size_t)iv.x * D_ + lane]
                    + w1 * vb[(size_t)iv.y * D_ + lane]
                    + w2 * vb[(size_t)iv.z * D_ + lane]
                    + w3 * vb[(size_t)iv.w * D_ + lane];
            out[(size_t)gr * D_ + lane] = o;

            if (lane < 4) {
                int   si = (lane == 0) ? iv.x : (lane == 1) ? iv.y
                         : (lane == 2) ? iv.z : iv.w;
                float sw = (lane == 0) ? w0 : (lane == 1) ? w1
                         : (lane == 2) ? w2 : w3;
                wout[(size_t)gr * L_ + si] = sw;   // w at Pmin slot is exactly 0
            }
        }
        __syncthreads();   // rep boundary: all reads done before next overwrite
    }
}

extern "C" void kernel_launch(void* const* d_in, const int* in_sizes, int n_in,
                              void* d_out, int out_size, void* d_ws, size_t ws_size,
                              hipStream_t stream) {
    const float* q = (const float*)d_in[0];
    const float* k = (const float*)d_in[1];
    const float* v = (const float*)d_in[2];

    float* out  = (float*)d_out;
    float* wout = out + (size_t)B_ * L_ * D_;

    _Float16* kext = (_Float16*)d_ws;   // 4 MiB

    cvt_k<<<(B_ * L_ * D_) / (8 * 256), 256, 0, stream>>>(k, kext);

    sdpa_all<<<1024, 256, 0, stream>>>(q, k, v, kext, out, wout);
}

// Round 13
// 80.064 us; speedup vs baseline: 3.0105x; 3.0105x over previous
//
#include <hip/hip_runtime.h>
#include <hip/hip_bf16.h>

// Geometry fixed by reference: B=16, Lq=Lk=2048, D=Dv=64, fp32.
// d_out = out [16,2048,64] ++ w [16,2048,2048].
#define B_ 16
#define L_ 2048
#define D_ 64
#define NROWS (B_ * L_)

typedef _Float16 half8 __attribute__((ext_vector_type(8)));
typedef float    f32x4 __attribute__((ext_vector_type(4)));

__device__ __forceinline__ float fexp2(float x) {
    float r; asm("v_exp_f32 %0, %1" : "=v"(r) : "v"(x)); return r;
}
__device__ __forceinline__ unsigned umed3(unsigned a, unsigned b, unsigned c) {
    unsigned d; asm("v_med3_u32 %0, %1, %2, %3" : "=v"(d) : "v"(a), "v"(b), "v"(c));
    return d;
}
// monotone float -> uint order-preserving transform
__device__ __forceinline__ unsigned fkey(float x) {
    unsigned b = __float_as_uint(x);
    return b ^ ((unsigned)(((int)b) >> 31) | 0x80000000u);
}

// ---------------------------------------------------------------------------
// Kernel P: K fp32 -> fp16, PRE-SWIZZLED into MFMA B-fragment order.
// Per 16-key tile bt: 2048-byte block; slot s = bt*128 + f*64 + l (16 B each)
// holds key row (bt*16 + (l&15)), d in [f*32 + (l>>4)*8, +8).
// The sweep then loads b0/b1 as LANE-CONTIGUOUS 1 KB reads (base + lane*16)
// instead of 16-line stride-128B gathers -> coalesced fast path.
// Per-lane values are bit-identical to the previous layout.
// Total slots = 16 batches * 128 tiles * 128 slots = 262144 -> grid 1024.
// ---------------------------------------------------------------------------
__global__ __launch_bounds__(256)
void cvt_k(const float* __restrict__ k, _Float16* __restrict__ kswz)
{
    int s  = blockIdx.x * 256 + threadIdx.x;   // slot id
    int bt = s >> 7;                           // global tile (b*128 + T)
    int f  = (s >> 6) & 1;                     // fragment (d-half)
    int l  = s & 63;                           // consumer lane
    int row = bt * 16 + (l & 15);              // global key row
    int d0  = f * 32 + ((l >> 4) << 3);

    const float* src = k + (size_t)row * D_ + d0;
    float4 a = *reinterpret_cast<const float4*>(src);
    float4 b = *reinterpret_cast<const float4*>(src + 4);
    half8 h = { (_Float16)a.x, (_Float16)a.y, (_Float16)a.z, (_Float16)a.w,
                (_Float16)b.x, (_Float16)b.y, (_Float16)b.z, (_Float16)b.w };
    *reinterpret_cast<half8*>(kswz + (size_t)s * 8) = h;
}

// ---------------------------------------------------------------------------
// Kernel A (R9 structure verbatim; only the kext load addresses changed):
// per block of 32 q-rows:
//   phase 1: fp16 MFMA score sweep + sum-exp2 + packed-uint top-4 ladder,
//            one interleaved NT fill-store per step (block's 256 KB w-slab);
//   phase 2: wk-pair merge via LDS + 16-lane tournament;
//   phase 3: exact fp32 rescore + weights + out + scatter.
// ---------------------------------------------------------------------------
__global__ __launch_bounds__(256)
void sdpa_all(const float* __restrict__ q,
              const float* __restrict__ k,
              const float* __restrict__ v,
              const _Float16* __restrict__ kswz,
              float* __restrict__ out,
              float* __restrict__ wout)
{
    __shared__ float Ms[2][64][21];   // wk-merge scratch (pad 21: bank-spread)
    __shared__ int4  Ri[32];          // per-row top-4 indices
    __shared__ float Rz[32];          // per-row Z (sum exp2)

    const int bid  = blockIdx.x;
    const int lbid = ((bid & 7) << 7) | (bid >> 3);   // XCD-contiguity swizzle
    const int tid  = threadIdx.x;
    const int b    = lbid >> 6;          // batch
    const int row0 = (lbid & 63) * 32;   // 32 rows per block
    const int w    = tid >> 6;
    const int lane = tid & 63;
    const int wr   = w & 1;              // row half (16 rows)
    const int wk   = w >> 1;             // key half (1024 keys)
    const int c    = lane & 15;
    const int g    = lane >> 4;

    const float CQ = 0.18033688011112042f;   // log2(e)/8
    float* wb = wout + ((size_t)b * L_ + row0) * L_;    // block's 256 KB slab

    // ---- Q fragment (A operand) ----
    half8 qf0, qf1;
    {
        const float* qr = q + ((size_t)(b * L_ + row0 + 16 * wr + c)) * D_ + 8 * g;
        float4 f0 = *reinterpret_cast<const float4*>(qr);
        float4 f1 = *reinterpret_cast<const float4*>(qr + 4);
        float4 f2 = *reinterpret_cast<const float4*>(qr + 32);
        float4 f3 = *reinterpret_cast<const float4*>(qr + 36);
        qf0 = half8{ (_Float16)(f0.x*CQ), (_Float16)(f0.y*CQ), (_Float16)(f0.z*CQ),
                     (_Float16)(f0.w*CQ), (_Float16)(f1.x*CQ), (_Float16)(f1.y*CQ),
                     (_Float16)(f1.z*CQ), (_Float16)(f1.w*CQ) };
        qf1 = half8{ (_Float16)(f2.x*CQ), (_Float16)(f2.y*CQ), (_Float16)(f2.z*CQ),
                     (_Float16)(f2.w*CQ), (_Float16)(f3.x*CQ), (_Float16)(f3.y*CQ),
                     (_Float16)(f3.z*CQ), (_Float16)(f3.w*CQ) };
    }

    // batch base in swizzled K: 128 tiles x 2048 B
    const char* ke = (const char*)kswz + (size_t)b * 262144;

    float    Z[4]  = {0.f, 0.f, 0.f, 0.f};
    unsigned tl[4][4];
    #pragma unroll
    for (int r = 0; r < 4; ++r)
        #pragma unroll
        for (int s = 0; s < 4; ++s) tl[r][s] = 0u;

    const f32x4 zz = {0.f, 0.f, 0.f, 0.f};
    f32x4* wb4 = reinterpret_cast<f32x4*>(wb);

    // sweep this wave-pair's 1024-key half, 16 keys (one tile) per step
    #pragma unroll 4
    for (int t = 0; t < 64; ++t) {
        const int T = wk * 64 + t;                        // tile id in batch
        const char* kp = ke + (size_t)T * 2048 + lane * 16;
        half8 b0 = *reinterpret_cast<const half8*>(kp);          // frag lo
        half8 b1 = *reinterpret_cast<const half8*>(kp + 1024);   // frag hi

        // interleaved slab zero-fill: 4 KB per block per step
        __builtin_nontemporal_store(zz, wb4 + t * 256 + tid);

        f32x4 a = {0.f, 0.f, 0.f, 0.f};
        a = __builtin_amdgcn_mfma_f32_16x16x32_f16(qf0, b0, a, 0, 0, 0);
        a = __builtin_amdgcn_mfma_f32_16x16x32_f16(qf1, b1, a, 0, 0, 0);

        const int kl = T * 16 + c;                        // key id in batch
        #pragma unroll
        for (int r = 0; r < 4; ++r) {
            float sp = a[r];                  // log2-domain score
            Z[r] += fexp2(sp);
            unsigned pk = (fkey(sp) & 0xFFFFF800u) | (unsigned)kl;
            unsigned n1 = umed3(pk, tl[r][0], tl[r][1]);
            unsigned n2 = umed3(pk, tl[r][1], tl[r][2]);
            unsigned n3 = umed3(pk, tl[r][2], tl[r][3]);
            tl[r][0] = max(tl[r][0], pk);
            tl[r][1] = n1; tl[r][2] = n2; tl[r][3] = n3;
        }
    }

    // ---- wk-pair merge through LDS ----
    if (wk == 1) {
        #pragma unroll
        for (int r = 0; r < 4; ++r) {
            Ms[wr][lane][r] = Z[r];
            #pragma unroll
            for (int s = 0; s < 4; ++s)
                Ms[wr][lane][4 + r * 4 + s] = __uint_as_float(tl[r][s]);
        }
    }
    __syncthreads();   // Ms published; own fill stores drained (vmcnt0+barrier)

    if (wk == 0) {
        #pragma unroll
        for (int r = 0; r < 4; ++r) {
            float Zr = Z[r] + Ms[wr][lane][r];
            #pragma unroll
            for (int s = 0; s < 4; ++s) {
                unsigned pk = __float_as_uint(Ms[wr][lane][4 + r * 4 + s]);
                unsigned n1 = umed3(pk, tl[r][0], tl[r][1]);
                unsigned n2 = umed3(pk, tl[r][1], tl[r][2]);
                unsigned n3 = umed3(pk, tl[r][2], tl[r][3]);
                tl[r][0] = max(tl[r][0], pk);
                tl[r][1] = n1; tl[r][2] = n2; tl[r][3] = n3;
            }
            #pragma unroll
            for (int m = 8; m; m >>= 1) Zr += __shfl_xor(Zr, m, 16);

            // 16-lane tournament: global top-4 (packed keys unique)
            int p = 0;
            unsigned win[4];
            #pragma unroll
            for (int t4 = 0; t4 < 4; ++t4) {
                unsigned cand = (p == 0) ? tl[r][0] : (p == 1) ? tl[r][1]
                              : (p == 2) ? tl[r][2] : (p == 3) ? tl[r][3] : 0u;
                unsigned mv = cand;
                #pragma unroll
                for (int m = 8; m; m >>= 1) {
                    unsigned ov = __shfl_xor(mv, m, 16);
                    mv = mv > ov ? mv : ov;
                }
                win[t4] = mv;
                if (cand == mv) ++p;
            }

            if (c == 0) {
                int rr = 16 * wr + 4 * g + r;
                Ri[rr] = make_int4((int)(win[0] & 2047u), (int)(win[1] & 2047u),
                                   (int)(win[2] & 2047u), (int)(win[3] & 2047u));
                Rz[rr] = Zr;
            }
        }
    }
    __syncthreads();

    // ---- phase 3: exact fp32 rescore + weights + out + scatter ----
    // 4 waves x 8 rows; lane group g = candidate slot, c = d/4 slot.
    const float* kb = k + (size_t)b * L_ * D_;
    const float* vb = v + (size_t)b * L_ * D_;
    #pragma unroll 2
    for (int rloc = 0; rloc < 8; ++rloc) {
        const int rr = w * 8 + rloc;
        const int gr = b * L_ + row0 + rr;
        int4  iv = Ri[rr];
        float Zr = Rz[rr];
        int myi = (g == 0) ? iv.x : (g == 1) ? iv.y : (g == 2) ? iv.z : iv.w;

        float4 qv = *reinterpret_cast<const float4*>(q + (size_t)gr * D_ + 4 * c);
        float4 kv = *reinterpret_cast<const float4*>(kb + (size_t)myi * D_ + 4 * c);
        float tp = qv.x * kv.x + qv.y * kv.y + qv.z * kv.z + qv.w * kv.w;
        #pragma unroll
        for (int m = 8; m; m >>= 1) tp += __shfl_xor(tp, m, 16);
        tp *= CQ;   // log2-domain exact score

        float t0 = __shfl(tp, 0), t1 = __shfl(tp, 16),
              t2 = __shfl(tp, 32), t3 = __shfl(tp, 48);

        // P_j = Z * p_j ; all w math scaled by Z (exactly equivalent)
        float P0 = fexp2(t0), P1 = fexp2(t1), P2 = fexp2(t2), P3 = fexp2(t3);
        float Pmin = fminf(fminf(P0, P1), fminf(P2, P3));
        float eZ = 1e-7f * Zr;
        float n0 = fmaxf(P0 - Pmin - eZ, 0.f);
        float n1 = fmaxf(P1 - Pmin - eZ, 0.f);
        float n2 = fmaxf(P2 - Pmin - eZ, 0.f);
        float n3 = fmaxf(P3 - Pmin - eZ, 0.f);
        float wi = 1.0f / (n0 + n1 + n2 + n3 + eZ);
        float w0 = n0 * wi, w1 = n1 * wi, w2 = n2 * wi, w3 = n3 * wi;

        float o = w0 * vb[(size_t)iv.x * D_ + lane]
                + w1 * vb[(size_t)iv.y * D_ + lane]
                + w2 * vb[(size_t)iv.z * D_ + lane]
                + w3 * vb[(size_t)iv.w * D_ + lane];
        out[(size_t)gr * D_ + lane] = o;

        if (lane < 4) {
            int   si = (lane == 0) ? iv.x : (lane == 1) ? iv.y
                     : (lane == 2) ? iv.z : iv.w;
            float sw = (lane == 0) ? w0 : (lane == 1) ? w1
                     : (lane == 2) ? w2 : w3;
            wout[(size_t)gr * L_ + si] = sw;   // w at Pmin slot is exactly 0
        }
    }
}

extern "C" void kernel_launch(void* const* d_in, const int* in_sizes, int n_in,
                              void* d_out, int out_size, void* d_ws, size_t ws_size,
                              hipStream_t stream) {
    const float* q = (const float*)d_in[0];
    const float* k = (const float*)d_in[1];
    const float* v = (const float*)d_in[2];

    float* out  = (float*)d_out;
    float* wout = out + (size_t)B_ * L_ * D_;

    _Float16* kswz = (_Float16*)d_ws;   // 4 MiB, B-fragment-swizzled K

    // slots = 16 batches * 128 tiles * 128 slots/tile = 262144 -> 1024 blocks
    cvt_k<<<1024, 256, 0, stream>>>(k, kswz);

    sdpa_all<<<1024, 256, 0, stream>>>(q, k, v, kswz, out, wout);
}